// Round 11
// baseline (98.682 us; speedup 1.0000x reference)
//
#include <hip/hip_runtime.h>
#include <hip/hip_bf16.h>
#include <stdint.h>

#define NPTS 131072
#define NBINS 2048   // 8 batches x 16 x 16 tiles (16px tiles)

typedef __attribute__((ext_vector_type(8))) short bf16x8;
typedef __attribute__((ext_vector_type(4))) float f32x4;
typedef __attribute__((ext_vector_type(8))) unsigned short u16x8;

__device__ inline unsigned short f32_to_bf16(float f) {
    union { __hip_bfloat16 h; unsigned short u; } cv;
    cv.h = __float2bfloat16(f);
    return cv.u;
}

// Kernel 1: blocks [0,2048): x NCHW f32 -> xt NHWC bf16.
// Blocks [2048,2066): weight -> fragment-ordered wfrag bf16 + zero xt pad.
// Block 2066: zero the sort histogram.
__global__ __launch_bounds__(256) void k_prep(const float* __restrict__ x,
                                              unsigned short* __restrict__ xt,
                                              const float* __restrict__ w,
                                              unsigned short* __restrict__ wfrag,
                                              int* __restrict__ hist) {
    if (blockIdx.x >= 2048) {
        if (blockIdx.x == 2066) {
#pragma unroll
            for (int i = 0; i < NBINS / 256; ++i)
                hist[threadIdx.x + i * 256] = 0;
            return;
        }
        int tid = (blockIdx.x - 2048) * 256 + threadIdx.x;  // 0..4607
        int ci = tid >> 6;
        int l  = tid & 63;
        int q    = ci >> 3;
        int half = (ci >> 2) & 1;
        int nn   = ci & 3;
        int c2   = nn * 16 + (l & 15);
        int cin0 = half * 32 + ((l >> 4) << 3);
        u16x8 o;
#pragma unroll
        for (int e = 0; e < 8; ++e)
            o[e] = f32_to_bf16(w[c2 * 576 + (cin0 + e) * 9 + q]);
        *(u16x8*)(wfrag + tid * 8) = o;
        if (blockIdx.x == 2048 && threadIdx.x < 8) {
            u16x8 z = {};
            *(u16x8*)(xt + (size_t)8 * 65536 * 64 + threadIdx.x * 8) = z;
        }
        return;
    }

    __shared__ float tile[64][65];
    int batch   = blockIdx.x >> 8;
    int pixbase = (blockIdx.x & 255) << 8;
    int t = threadIdx.x;
    const float* xb = x + (size_t)batch * 64 * 65536;

    int c0  = t >> 4;
    int px4 = (t & 15) << 2;
    int c8  = (t & 7) << 3;
    int pp  = t >> 3;

    for (int sub = 0; sub < 4; ++sub) {
        int pix0 = pixbase + (sub << 6);
        if (sub) __syncthreads();
#pragma unroll
        for (int i = 0; i < 4; ++i) {
            int c = c0 + i * 16;
            float4 v = *(const float4*)(xb + (size_t)c * 65536 + pix0 + px4);
            tile[c][px4 + 0] = v.x; tile[c][px4 + 1] = v.y;
            tile[c][px4 + 2] = v.z; tile[c][px4 + 3] = v.w;
        }
        __syncthreads();
#pragma unroll
        for (int h = 0; h < 2; ++h) {
            int pix = pp + h * 32;
            u16x8 o;
#pragma unroll
            for (int i = 0; i < 8; ++i) o[i] = f32_to_bf16(tile[c8 + i][pix]);
            *(u16x8*)(xt + ((size_t)(batch * 65536 + pix0 + pix) * 64 + c8)) = o;
        }
    }
}

__device__ inline int point_key(int b, int y, int x) {
    return (b << 8) | ((y >> 4) << 4) | (x >> 4);
}

// Histogram of point tile-keys
__global__ __launch_bounds__(256) void k_hist(const int* __restrict__ indices,
                                              int* __restrict__ hist) {
    int p = blockIdx.x * 256 + threadIdx.x;
    int b = indices[p * 3], y = indices[p * 3 + 1], x = indices[p * 3 + 2];
    atomicAdd(&hist[point_key(b, y, x)], 1);
}

// Exclusive scan of 2048-bin histogram -> cursor (scatter start positions)
__global__ __launch_bounds__(256) void k_scan(const int* __restrict__ hist,
                                              int* __restrict__ cursor) {
    __shared__ int tsum[256];
    int t = threadIdx.x;
    int local[8];
    int s = 0;
#pragma unroll
    for (int i = 0; i < 8; ++i) { local[i] = hist[t * 8 + i]; s += local[i]; }
    tsum[t] = s;
    __syncthreads();
    for (int off = 1; off < 256; off <<= 1) {
        int u = (t >= off) ? tsum[t - off] : 0;
        __syncthreads();
        tsum[t] += u;
        __syncthreads();
    }
    int running = tsum[t] - s;  // exclusive prefix of this thread's 8 bins
#pragma unroll
    for (int i = 0; i < 8; ++i) { cursor[t * 8 + i] = running; running += local[i]; }
}

// Scatter points into bin-sorted order as (b,y,x,pt) tuples
__global__ __launch_bounds__(256) void k_scatter(const int* __restrict__ indices,
                                                 int* __restrict__ cursor,
                                                 int4* __restrict__ sorted) {
    int p = blockIdx.x * 256 + threadIdx.x;
    int b = indices[p * 3], y = indices[p * 3 + 1], x = indices[p * 3 + 2];
    int slot = atomicAdd(&cursor[point_key(b, y, x)], 1);
    sorted[slot] = make_int4(b, y, x, p);
}

// Kernel 5: gather + GEMM over spatially-sorted points. 512 thr = 8 waves,
// wave owns 16 sorted points; deep prefetch (all 18 gather loads up front).
// Sorted order -> block's gather spans ~2 adjacent 16x16 tiles -> L2-local.
__global__ __launch_bounds__(512, 4) void k_gather_gemm(
    const unsigned short* __restrict__ xt,
    const unsigned short* __restrict__ wfrag,
    const int4* __restrict__ sorted,
    const float* __restrict__ bias,
    float* __restrict__ out) {
    __shared__ unsigned short wlds[72 * 512];  // 73728 B

    int t = threadIdx.x;
    int w = t >> 6;
    int l = t & 63;
    int lo = l & 15;
    int hi = l >> 4;

    // XCD-chunked bijective swizzle: 1024 blocks, 8 XCDs -> each XCD gets a
    // contiguous run of 128 sorted blocks (one spatial region per XCD L2).
    int sb = (blockIdx.x & 7) * 128 + (blockIdx.x >> 3);

#pragma unroll
    for (int i = 0; i < 9; ++i) {
        int m = t + i * 512;
        *(u16x8*)(&wlds[m * 8]) = *(const u16x8*)(wfrag + m * 8);
    }

    int slot = sb * 128 + w * 16 + lo;
    int4 s4 = sorted[slot];
    int b = s4.x, yi = s4.y, xi = s4.z;

    const uint32_t PADOFF = (uint32_t)8 * 65536 * 128;  // zeroed OOB pad
    uint32_t sub = (uint32_t)(hi << 4);

    uint32_t off[9];
#pragma unroll
    for (int q = 0; q < 9; ++q) {
        int yy = yi + (q / 3) - 1;
        int xx = xi + (q % 3) - 1;
        bool v = ((unsigned)yy < 256u) & ((unsigned)xx < 256u);
        uint32_t pix = ((uint32_t)b << 16) + ((uint32_t)(yy & 255) << 8) + (uint32_t)(xx & 255);
        off[q] = (v ? pix * 128u : PADOFF) + sub;
    }

    bf16x8 a[18];
#pragma unroll
    for (int q = 0; q < 9; ++q) {
        a[2 * q + 0] = (bf16x8)(*(const u16x8*)((const char*)xt + off[q]));
        a[2 * q + 1] = (bf16x8)(*(const u16x8*)((const char*)xt + off[q] + 64));
    }

    f32x4 acc[4];
#pragma unroll
    for (int nn = 0; nn < 4; ++nn) acc[nn] = (f32x4)0.0f;

    __syncthreads();  // wlds ready

#pragma unroll
    for (int q = 0; q < 9; ++q) {
#pragma unroll
        for (int h = 0; h < 2; ++h) {
            const unsigned short* base = &wlds[q * 4096 + h * 2048];
#pragma unroll
            for (int nn = 0; nn < 4; ++nn) {
                bf16x8 bf = *(const bf16x8*)(base + nn * 512 + l * 8);
                acc[nn] = __builtin_amdgcn_mfma_f32_16x16x32_bf16(a[2 * q + h], bf, acc[nn], 0, 0, 0);
            }
        }
    }

    // Epilogue: row r of D-frag = point slot hi*4+r; its original index from
    // sorted[].w routes the write to the un-sorted out row.
    int slotbase = sb * 128 + w * 16 + (hi << 2);
    int pt[4];
#pragma unroll
    for (int r = 0; r < 4; ++r) pt[r] = sorted[slotbase + r].w;
#pragma unroll
    for (int nn = 0; nn < 4; ++nn) {
        float bv = bias[nn * 16 + lo];
#pragma unroll
        for (int r = 0; r < 4; ++r) {
            out[(size_t)pt[r] * 64 + nn * 16 + lo] = acc[nn][r] + bv;
        }
    }
}

// Fallback if workspace too small: naive direct conv (correct, slow)
__global__ void k_naive(const float* __restrict__ x, const int* __restrict__ idx,
                        const float* __restrict__ w, const float* __restrict__ bias,
                        float* __restrict__ out) {
    int i = blockIdx.x * 256 + threadIdx.x;
    if (i >= NPTS * 64) return;
    int p = i >> 6, c2 = i & 63;
    int b = idx[p * 3], yi = idx[p * 3 + 1], xi = idx[p * 3 + 2];
    float acc = bias[c2];
    for (int c = 0; c < 64; ++c) {
        const float* xp = x + ((size_t)(b * 64 + c) << 16);
        const float* wp = w + (c2 * 64 + c) * 9;
        for (int dy = 0; dy < 3; ++dy) {
            int yy = yi + dy - 1;
            if ((unsigned)yy >= 256u) continue;
            for (int dx = 0; dx < 3; ++dx) {
                int xx = xi + dx - 1;
                if ((unsigned)xx >= 256u) continue;
                acc += xp[(yy << 8) + xx] * wp[dy * 3 + dx];
            }
        }
    }
    out[i] = acc;
}

extern "C" void kernel_launch(void* const* d_in, const int* in_sizes, int n_in,
                              void* d_out, int out_size, void* d_ws, size_t ws_size,
                              hipStream_t stream) {
    const float* x       = (const float*)d_in[0];
    const int*   indices = (const int*)d_in[1];
    const float* weight  = (const float*)d_in[2];
    const float* bias    = (const float*)d_in[3];
    float* out = (float*)d_out;

    size_t xt_bytes     = (size_t)8 * 65536 * 64 * 2 + 128;  // incl. OOB pad
    size_t wfrag_bytes  = (size_t)72 * 1024;
    size_t hist_bytes   = (size_t)NBINS * 4;
    size_t cursor_bytes = (size_t)NBINS * 4;
    size_t sorted_bytes = (size_t)NPTS * 16;
    size_t need = xt_bytes + wfrag_bytes + hist_bytes + cursor_bytes + sorted_bytes;
    if (ws_size < need) {
        k_naive<<<(NPTS * 64 + 255) / 256, 256, 0, stream>>>(x, indices, weight, bias, out);
        return;
    }
    char* p = (char*)d_ws;
    unsigned short* xt    = (unsigned short*)p;  p += xt_bytes;
    unsigned short* wfrag = (unsigned short*)p;  p += wfrag_bytes;
    int*            hist  = (int*)p;             p += hist_bytes;
    int*            cursor= (int*)p;             p += cursor_bytes;
    int4*           sorted= (int4*)p;

    k_prep<<<2048 + 18 + 1, 256, 0, stream>>>(x, xt, weight, wfrag, hist);
    k_hist<<<NPTS / 256, 256, 0, stream>>>(indices, hist);
    k_scan<<<1, 256, 0, stream>>>(hist, cursor);
    k_scatter<<<NPTS / 256, 256, 0, stream>>>(indices, cursor, sorted);
    k_gather_gemm<<<NPTS / 128, 512, 0, stream>>>(xt, wfrag, sorted, bias, out);
}

// Round 12
// 63.752 us; speedup vs baseline: 1.5479x; 1.5479x over previous
//
#include <hip/hip_runtime.h>
#include <hip/hip_bf16.h>
#include <stdint.h>

#define NPTS 131072

typedef __attribute__((ext_vector_type(8))) short bf16x8;
typedef __attribute__((ext_vector_type(4))) float f32x4;
typedef __attribute__((ext_vector_type(8))) unsigned short u16x8;

__device__ inline unsigned short f32_to_bf16(float f) {
    union { float f; uint32_t u; } v; v.f = f;
    uint32_t u = v.u;
    return (unsigned short)((u + 0x7FFFu + ((u >> 16) & 1u)) >> 16);
}

// Kernel 1 (fused): blocks [0,8192): x NCHW f32 -> xt NHWC bf16.
// Blocks [8192, 8210): weight (64,64,3,3) f32 -> fragment-ordered wfrag bf16,
//                      plus zero the 128 B OOB pad at the end of xt.
// wfrag chunk ci = q*8 + half*4 + nn (1 KB each): lane l, elem e holds
//   w[c2=nn*16+(l&15)][cin=half*32+(l>>4)*8+e][q]   (q = dy*3+dx)
__global__ __launch_bounds__(256) void k_transpose(const float* __restrict__ x,
                                                   unsigned short* __restrict__ xt,
                                                   const float* __restrict__ w,
                                                   unsigned short* __restrict__ wfrag) {
    if (blockIdx.x >= 8192) {
        int tid = (blockIdx.x - 8192) * 256 + threadIdx.x;  // 0..4607
        if (tid < 4608) {
            int ci = tid >> 6;          // 0..71
            int l  = tid & 63;
            int q    = ci >> 3;
            int half = (ci >> 2) & 1;
            int nn   = ci & 3;
            int c2   = nn * 16 + (l & 15);
            int cin0 = half * 32 + ((l >> 4) << 3);
            u16x8 o;
#pragma unroll
            for (int e = 0; e < 8; ++e)
                o[e] = f32_to_bf16(w[c2 * 576 + (cin0 + e) * 9 + q]);
            *(u16x8*)(wfrag + tid * 8) = o;
        }
        if (blockIdx.x == 8192 && threadIdx.x < 8) {
            u16x8 z = {};
            *(u16x8*)(xt + (size_t)8 * 65536 * 64 + threadIdx.x * 8) = z;
        }
        return;
    }

    __shared__ float tile[64][65];
    int bid = blockIdx.x;
    int batch = bid >> 10;
    int pix0 = (bid & 1023) << 6;
    int t = threadIdx.x;
    const float* xb = x + (size_t)batch * 64 * 65536;

    int c0 = t >> 4;
    int px = (t & 15) << 2;
#pragma unroll
    for (int i = 0; i < 4; ++i) {
        int c = c0 + i * 16;
        float4 v = *(const float4*)(xb + (size_t)c * 65536 + pix0 + px);
        tile[c][px + 0] = v.x; tile[c][px + 1] = v.y;
        tile[c][px + 2] = v.z; tile[c][px + 3] = v.w;
    }
    __syncthreads();

    int c8 = (t & 7) << 3;
    int pp = t >> 3;
#pragma unroll
    for (int h = 0; h < 2; ++h) {
        int pix = pp + h * 32;
        u16x8 o;
#pragma unroll
        for (int i = 0; i < 8; ++i) o[i] = f32_to_bf16(tile[c8 + i][pix]);
        *(u16x8*)(xt + ((size_t)(batch * 65536 + pix0 + pix) * 64 + c8)) = o;
    }
}

// Kernel 3: gather + GEMM. 512 threads = 8 waves; each wave owns 32 points
// (two 16-row M-tiles sharing every B-fragment). A gathered global->regs with
// 1-pixel prefetch; OOB pixels read the zero pad (no per-load selects).
// Weights in LDS, fragment-ordered -> lane-linear ds_read_b128, zero addr VALU.
__global__ __launch_bounds__(512, 4) void k_gather_gemm(
    const unsigned short* __restrict__ xt,
    const unsigned short* __restrict__ wfrag,
    const int* __restrict__ indices,
    const float* __restrict__ bias,
    float* __restrict__ out) {
    __shared__ unsigned short wlds[72 * 512];  // 73728 B

    int t = threadIdx.x;
    int w = t >> 6;
    int l = t & 63;
    int lo = l & 15;
    int hi = l >> 4;

    // Stage weights: 4608 16B-chunks, 9 per thread, fully coalesced
#pragma unroll
    for (int i = 0; i < 9; ++i) {
        int m = t + i * 512;
        *(u16x8*)(&wlds[m * 8]) = *(const u16x8*)(wfrag + m * 8);
    }

    int p0 = blockIdx.x * 256 + w * 32;
    int pA = p0 + lo, pB = p0 + 16 + lo;
    int bA = indices[pA * 3], yA = indices[pA * 3 + 1], xA = indices[pA * 3 + 2];
    int bB = indices[pB * 3], yB = indices[pB * 3 + 1], xB = indices[pB * 3 + 2];

    const uint32_t PADOFF = (uint32_t)8 * 65536 * 128;  // byte offset of zero pad
    uint32_t sub = (uint32_t)(hi << 4);

    auto offq = [&](int b, int y, int x, int q) -> uint32_t {
        int yy = y + (q / 3) - 1;
        int xx = x + (q % 3) - 1;
        bool v = ((unsigned)yy < 256u) & ((unsigned)xx < 256u);
        uint32_t pix = ((uint32_t)b << 16) + ((uint32_t)(yy & 255) << 8) + (uint32_t)(xx & 255);
        return (v ? pix * 128u : PADOFF) + sub;
    };
    auto lda = [&](uint32_t o) -> bf16x8 {
        return (bf16x8)(*(const u16x8*)((const char*)xt + o));
    };

    f32x4 acc[2][4];
#pragma unroll
    for (int m = 0; m < 2; ++m)
#pragma unroll
        for (int nn = 0; nn < 4; ++nn) acc[m][nn] = (f32x4)0.0f;

    __syncthreads();  // wlds ready

    uint32_t oA = offq(bA, yA, xA, 0), oB = offq(bB, yB, xB, 0);
    bf16x8 a00 = lda(oA), a01 = lda(oA + 64);   // tile0 half0/half1
    bf16x8 a10 = lda(oB), a11 = lda(oB + 64);   // tile1

#pragma unroll
    for (int q = 0; q < 9; ++q) {
        bf16x8 n00, n01, n10, n11;
        if (q < 8) {
            uint32_t nA = offq(bA, yA, xA, q + 1), nB = offq(bB, yB, xB, q + 1);
            n00 = lda(nA); n01 = lda(nA + 64);
            n10 = lda(nB); n11 = lda(nB + 64);
        }
        const unsigned short* base = &wlds[q * 4096];  // q's 8 chunks (u16 idx)
#pragma unroll
        for (int nn = 0; nn < 4; ++nn) {
            bf16x8 b0 = *(const bf16x8*)(base + nn * 512 + l * 8);          // half0
            acc[0][nn] = __builtin_amdgcn_mfma_f32_16x16x32_bf16(a00, b0, acc[0][nn], 0, 0, 0);
            acc[1][nn] = __builtin_amdgcn_mfma_f32_16x16x32_bf16(a10, b0, acc[1][nn], 0, 0, 0);
        }
#pragma unroll
        for (int nn = 0; nn < 4; ++nn) {
            bf16x8 b1 = *(const bf16x8*)(base + 2048 + nn * 512 + l * 8);   // half1
            acc[0][nn] = __builtin_amdgcn_mfma_f32_16x16x32_bf16(a01, b1, acc[0][nn], 0, 0, 0);
            acc[1][nn] = __builtin_amdgcn_mfma_f32_16x16x32_bf16(a11, b1, acc[1][nn], 0, 0, 0);
        }
        if (q < 8) { a00 = n00; a01 = n01; a10 = n10; a11 = n11; }
    }

    // Epilogue: D col = lo (channel within nn-tile), row = hi*4 + r
    int rbase = blockIdx.x * 256 + w * 32 + (hi << 2);
#pragma unroll
    for (int nn = 0; nn < 4; ++nn) {
        float bv = bias[nn * 16 + lo];
#pragma unroll
        for (int m = 0; m < 2; ++m) {
#pragma unroll
            for (int r = 0; r < 4; ++r) {
                out[(size_t)(rbase + m * 16 + r) * 64 + nn * 16 + lo] = acc[m][nn][r] + bv;
            }
        }
    }
}

// Fallback if workspace too small: naive direct conv (correct, slow)
__global__ void k_naive(const float* __restrict__ x, const int* __restrict__ idx,
                        const float* __restrict__ w, const float* __restrict__ bias,
                        float* __restrict__ out) {
    int i = blockIdx.x * 256 + threadIdx.x;
    if (i >= NPTS * 64) return;
    int p = i >> 6, c2 = i & 63;
    int b = idx[p * 3], yi = idx[p * 3 + 1], xi = idx[p * 3 + 2];
    float acc = bias[c2];
    for (int c = 0; c < 64; ++c) {
        const float* xp = x + ((size_t)(b * 64 + c) << 16);
        const float* wp = w + (c2 * 64 + c) * 9;
        for (int dy = 0; dy < 3; ++dy) {
            int yy = yi + dy - 1;
            if ((unsigned)yy >= 256u) continue;
            for (int dx = 0; dx < 3; ++dx) {
                int xx = xi + dx - 1;
                if ((unsigned)xx >= 256u) continue;
                acc += xp[(yy << 8) + xx] * wp[dy * 3 + dx];
            }
        }
    }
    out[i] = acc;
}

extern "C" void kernel_launch(void* const* d_in, const int* in_sizes, int n_in,
                              void* d_out, int out_size, void* d_ws, size_t ws_size,
                              hipStream_t stream) {
    const float* x       = (const float*)d_in[0];
    const int*   indices = (const int*)d_in[1];
    const float* weight  = (const float*)d_in[2];
    const float* bias    = (const float*)d_in[3];
    float* out = (float*)d_out;

    size_t xt_bytes = (size_t)8 * 65536 * 64 * 2 + 128;   // incl. 128 B zero pad
    size_t need = xt_bytes + (size_t)72 * 1024;           // + wfrag
    if (ws_size < need) {
        k_naive<<<(NPTS * 64 + 255) / 256, 256, 0, stream>>>(x, indices, weight, bias, out);
        return;
    }
    unsigned short* xt    = (unsigned short*)d_ws;
    unsigned short* wfrag = (unsigned short*)((char*)d_ws + xt_bytes);

    k_transpose<<<8192 + 18, 256, 0, stream>>>(x, xt, weight, wfrag);
    k_gather_gemm<<<NPTS / 256, 512, 0, stream>>>(xt, wfrag, indices, bias, out);
}